// Round 6
// baseline (288.530 us; speedup 1.0000x reference)
//
#include <hip/hip_runtime.h>
#include <hip/hip_bf16.h>

// Problem constants
#define B_  128
#define T_  512
#define D_  400
#define NV  1024
#define NA  128

// Main-kernel tiling
#define LDH  424   // Hbf/LDS row stride (bf16): 848 B
#define NT   32    // t-tile (32x848B = 27136 B LDS -> 3+ blocks/CU)
#define MV   128   // v rows per block (4 waves x 32)
#define MAIN_BLOCKS 1024

typedef __bf16 bf16_t;
typedef bf16_t bf16x8 __attribute__((ext_vector_type(8)));
typedef bf16_t bf16x4 __attribute__((ext_vector_type(4)));
typedef float  floatx4 __attribute__((ext_vector_type(4)));

__device__ inline void async_copy16(const void* g, void* l) {
    __builtin_amdgcn_global_load_lds(
        (const __attribute__((address_space(1))) unsigned int*)g,
        (__attribute__((address_space(3))) unsigned int*)l, 16, 0, 0);
}

__device__ inline float dot4(float4 a, float4 b) {
    return a.x * b.x + a.y * b.y + a.z * b.z + a.w * b.w;
}

// ---------------------------------------------------------------------------
// Fused prep kernel:
//   blocks [0, B*T/4):            hw[b,t] = H[b,t,:].W  and  Hbf row (bf16, padded)
//   blocks [B*T/4, +B*NA/4):      s2[b,a] = C_acts[b,a,:] . c_utt[b,:]
// ---------------------------------------------------------------------------
__global__ __launch_bounds__(256) void prep_kernel(const float* __restrict__ H,
                                                   const float* __restrict__ W,
                                                   const float* __restrict__ Ca,
                                                   const float* __restrict__ cu,
                                                   float* __restrict__ hw,
                                                   bf16_t* __restrict__ Hbf,
                                                   float* __restrict__ s2) {
    int wave = threadIdx.x >> 6;
    int lane = threadIdx.x & 63;
    if (blockIdx.x < B_ * T_ / 4) {
        long row = (long)blockIdx.x * 4 + wave;          // [0, B*T)
        const float* h = H + row * D_;
        bf16_t* orow = Hbf + row * (long)LDH;
        float acc = 0.f;
        if (lane < 50) {
            const float4* p  = (const float4*)(h + lane * 8);
            const float4* wp = (const float4*)(W + lane * 8);
            float4 x = p[0], y = p[1];
            acc = dot4(x, wp[0]) + dot4(y, wp[1]);
            bf16x8 f;
            f[0] = (bf16_t)x.x; f[1] = (bf16_t)x.y; f[2] = (bf16_t)x.z; f[3] = (bf16_t)x.w;
            f[4] = (bf16_t)y.x; f[5] = (bf16_t)y.y; f[6] = (bf16_t)y.z; f[7] = (bf16_t)y.w;
            *(bf16x8*)(orow + lane * 8) = f;
        } else if (lane < 53) {
            bf16x8 z;
#pragma unroll
            for (int j = 0; j < 8; ++j) z[j] = (bf16_t)0.0f;
            *(bf16x8*)(orow + 400 + (lane - 50) * 8) = z;
        }
#pragma unroll
        for (int off = 1; off < 64; off <<= 1) acc += __shfl_xor(acc, off, 64);
        if (lane == 0) hw[row] = acc;
    } else {
        long row = (long)(blockIdx.x - B_ * T_ / 4) * 4 + wave;   // [0, B*NA)
        int b = (int)(row >> 7);
        const float4* a4 = (const float4*)(Ca + row * (long)D_);
        const float4* c4 = (const float4*)(cu + (long)b * D_);
        float acc = dot4(a4[lane], c4[lane]);
        if (lane < 36) acc += dot4(a4[lane + 64], c4[lane + 64]);
#pragma unroll
        for (int off = 1; off < 64; off <<= 1) acc += __shfl_xor(acc, off, 64);
        if (lane == 0) s2[row] = acc;
    }
}

// ---------------------------------------------------------------------------
// Fallback prep (no workspace for Hbf): hw + s2 only
// ---------------------------------------------------------------------------
__global__ __launch_bounds__(256) void prep_nb_kernel(const float* __restrict__ H,
                                                      const float* __restrict__ W,
                                                      const float* __restrict__ Ca,
                                                      const float* __restrict__ cu,
                                                      float* __restrict__ hw,
                                                      float* __restrict__ s2) {
    int wave = threadIdx.x >> 6;
    int lane = threadIdx.x & 63;
    if (blockIdx.x < B_ * T_ / 4) {
        long row = (long)blockIdx.x * 4 + wave;
        const float* h = H + row * D_;
        float acc = 0.f;
        for (int k = lane; k < D_; k += 64) acc += h[k] * W[k];
#pragma unroll
        for (int off = 1; off < 64; off <<= 1) acc += __shfl_xor(acc, off, 64);
        if (lane == 0) hw[row] = acc;
    } else {
        long row = (long)(blockIdx.x - B_ * T_ / 4) * 4 + wave;
        int b = (int)(row >> 7);
        const float4* a4 = (const float4*)(Ca + row * (long)D_);
        const float4* c4 = (const float4*)(cu + (long)b * D_);
        float acc = dot4(a4[lane], c4[lane]);
        if (lane < 36) acc += dot4(a4[lane + 64], c4[lane + 64]);
#pragma unroll
        for (int off = 1; off < 64; off <<= 1) acc += __shfl_xor(acc, off, 64);
        if (lane == 0) s2[row] = acc;
    }
}

// ---------------------------------------------------------------------------
// qacts: per-b softmax of s2 + q_acts[b,:] = sum_a p[a] * C_acts[b,a,:]
// (barriers in uniform control flow — R4 bugfix retained)
// ---------------------------------------------------------------------------
__global__ __launch_bounds__(256) void qacts_kernel(const float* __restrict__ s2,
                                                    const float* __restrict__ Ca,
                                                    float* __restrict__ q_ws) {
    __shared__ float p_lds[NA];
    __shared__ float red[8];
    __shared__ __align__(16) float4 part[100];
    int b = blockIdx.x;
    int tid = threadIdx.x, wave = tid >> 6, lane = tid & 63;

    float s = (tid < NA) ? s2[(long)b * NA + tid] : -3.0e38f;
    float m = s;
#pragma unroll
    for (int off = 1; off < 64; off <<= 1) m = fmaxf(m, __shfl_xor(m, off, 64));
    if (lane == 0) red[wave] = m;
    __syncthreads();
    m = fmaxf(red[0], red[1]);
    float e = (tid < NA) ? __expf(s - m) : 0.f;
    float sum = e;
#pragma unroll
    for (int off = 1; off < 64; off <<= 1) sum += __shfl_xor(sum, off, 64);
    if (lane == 0) red[4 + wave] = sum;
    __syncthreads();
    float S = red[4] + red[5];
    if (tid < NA) p_lds[tid] = e / S;
    __syncthreads();

    int c4 = tid % 100;
    int half = tid / 100;
    float4 acc0 = {0.f, 0.f, 0.f, 0.f};
    if (tid < 200) {
        const float4* Cb4 = (const float4*)(Ca + (size_t)b * NA * D_);
        float4 acc1 = {0.f, 0.f, 0.f, 0.f};
        int a0 = half * 64;
#pragma unroll 4
        for (int a = 0; a < 64; a += 2) {
            float p0 = p_lds[a0 + a], p1 = p_lds[a0 + a + 1];
            float4 x0 = Cb4[(size_t)(a0 + a) * 100 + c4];
            float4 x1 = Cb4[(size_t)(a0 + a + 1) * 100 + c4];
            acc0.x += p0 * x0.x; acc0.y += p0 * x0.y; acc0.z += p0 * x0.z; acc0.w += p0 * x0.w;
            acc1.x += p1 * x1.x; acc1.y += p1 * x1.y; acc1.z += p1 * x1.z; acc1.w += p1 * x1.w;
        }
        acc0.x += acc1.x; acc0.y += acc1.y; acc0.z += acc1.z; acc0.w += acc1.w;
        if (half == 1) part[c4] = acc0;
    }
    __syncthreads();
    if (tid < 100) {
        float4 o = part[c4];
        o.x += acc0.x; o.y += acc0.y; o.z += acc0.z; o.w += acc0.w;
        ((float4*)(q_ws + (size_t)b * D_))[c4] = o;
    }
}

// ---------------------------------------------------------------------------
// Fused main + yacts.
//   blocks [0, 1024):  flash-style scalar-value attention (y_utts)
//   blocks [1024, +8192): y_acts = q_acts . vals^T (one wave per 4 v-rows)
// main: NT=32 tiles, 4 waves x 32 v (2 A-sets), per-LANE shared-max online
// softmax (m is only a per-row-consistent offset; the epilogue butterfly
// merges heterogeneous m exactly), DMA staging via global_load_lds w=16.
// ---------------------------------------------------------------------------
template<int PRE>
__global__ __launch_bounds__(256, 3) void main_kernel(const float* __restrict__ H,
                                                      const bf16_t* __restrict__ Hbf,
                                                      const float* __restrict__ Cv,
                                                      const float* __restrict__ hw,
                                                      const float* __restrict__ bs,
                                                      const int* __restrict__ lens,
                                                      const float* __restrict__ q_ws,
                                                      float* __restrict__ out) {
    __shared__ bf16_t h_lds[NT * LDH + 256];   // +512B pad for DMA tail chunk
    __shared__ float hw_lds[NT];

    int tid = threadIdx.x;
    int wave = tid >> 6, lane = tid & 63;

    if (blockIdx.x >= MAIN_BLOCKS) {
        // ---- yacts part ----
        long grp = (long)(blockIdx.x - MAIN_BLOCKS) * 4 + wave;   // [0, B*NV/4)
        int b = (int)(grp >> 8);
        int v0 = (int)(grp & 255) * 4;
        const float4* q4 = (const float4*)(q_ws + (size_t)b * D_);
        float4 qa = q4[lane];
        float4 qb = (lane < 36) ? q4[lane + 64] : make_float4(0.f, 0.f, 0.f, 0.f);
        float acc[4];
#pragma unroll
        for (int r = 0; r < 4; ++r) {
            const float4* v4 = (const float4*)(Cv + (size_t)(v0 + r) * D_);
            acc[r] = dot4(v4[lane], qa);
            if (lane < 36) acc[r] += dot4(v4[lane + 64], qb);
        }
#pragma unroll
        for (int off = 1; off < 64; off <<= 1) {
#pragma unroll
            for (int r = 0; r < 4; ++r) acc[r] += __shfl_xor(acc[r], off, 64);
        }
        if (lane == 0) {
            float4 o = make_float4(acc[0], acc[1], acc[2], acc[3]);
            *(float4*)(out + (size_t)B_ * NV + (size_t)b * NV + v0) = o;
        }
        return;
    }

    // ---- main part ----
    int i = blockIdx.x;
    int xcd = i & 7, vc = (i >> 3) & 7, bb = i >> 6;
    int b = xcd + 8 * bb;            // 0..127; 8 v-chunks of one b share an XCD
    int vbase = vc * MV;

    int lrow = lane & 15, quad = lane >> 4;
    int len = lens[b];
    float b0 = bs[0];

    if (!PRE) {
        for (int idx = tid; idx < NT * (LDH - D_); idx += 256) {
            int r = idx / (LDH - D_), c = idx % (LDH - D_);
            h_lds[r * LDH + D_ + c] = (bf16_t)0.0f;
        }
    }

    // A fragments: 2 sets x 13 k-steps (vals rows f32 -> bf16), 104 VGPRs
    bf16x8 afrag[2][13];
#pragma unroll
    for (int set = 0; set < 2; ++set) {
        const float* vrow = Cv + (size_t)(vbase + wave * 32 + set * 16 + lrow) * D_;
#pragma unroll
        for (int kk = 0; kk < 13; ++kk) {
            int k0 = kk * 32 + quad * 8;
            bf16x8 f;
            if (k0 >= D_) {
#pragma unroll
                for (int j = 0; j < 8; ++j) f[j] = (bf16_t)0.0f;
            } else {
                const float4* p = (const float4*)(vrow + k0);
                float4 x = p[0], y = p[1];
                f[0] = (bf16_t)x.x; f[1] = (bf16_t)x.y;
                f[2] = (bf16_t)x.z; f[3] = (bf16_t)x.w;
                f[4] = (bf16_t)y.x; f[5] = (bf16_t)y.y;
                f[6] = (bf16_t)y.z; f[7] = (bf16_t)y.w;
            }
            afrag[set][kk] = f;
        }
    }

    // per-lane online-softmax: ONE shared max per lane + (l,a) per row
    float m_s = -3.0e38f;
    float l_s[2][4], a_s[2][4];
#pragma unroll
    for (int set = 0; set < 2; ++set)
#pragma unroll
        for (int r = 0; r < 4; ++r) { l_s[set][r] = 0.f; a_s[set][r] = 0.f; }

    int ntiles = (len + NT - 1) / NT;   // len >= T/2 -> >= 8, uniform per block
    const float* Hb = H + (size_t)b * T_ * D_;
    const bf16_t* Hbfb = Hbf + (size_t)b * T_ * LDH;

    for (int tt = 0; tt < ntiles; ++tt) {
        int t0 = tt * NT;
        __syncthreads();
        if (PRE) {
            // tile = contiguous 32*848 B = 26.5 KB; 27 chunks of 1024 B (last
            // half-garbage -> lands in the LDS pad, never read)
            const char* gt = (const char*)(Hbfb + (size_t)t0 * LDH);
            char* lt = (char*)h_lds;
#pragma unroll 1
            for (int c = wave; c < 27; c += 4)
                async_copy16(gt + c * 1024 + lane * 16, lt + c * 1024 + lane * 16);
        } else {
            for (int idx = tid; idx < NT * (D_ / 4); idx += 256) {
                int r = idx / (D_ / 4), c4 = idx % (D_ / 4);
                float4 x = *(const float4*)(Hb + (size_t)(t0 + r) * D_ + c4 * 4);
                bf16x4 f;
                f[0] = (bf16_t)x.x; f[1] = (bf16_t)x.y;
                f[2] = (bf16_t)x.z; f[3] = (bf16_t)x.w;
                *(bf16x4*)(&h_lds[r * LDH + c4 * 4]) = f;
            }
        }
        if (tid < NT) hw_lds[tid] = hw[(size_t)b * T_ + t0 + tid];
        __syncthreads();

        // S tile: 32 v-rows x 32 t-cols per wave; one B-read feeds 2 MFMAs
        floatx4 c[2][2];
        floatx4 zero4 = {0.f, 0.f, 0.f, 0.f};
#pragma unroll
        for (int set = 0; set < 2; ++set)
#pragma unroll
            for (int s = 0; s < 2; ++s) c[set][s] = zero4;

#pragma unroll
        for (int kk = 0; kk < 13; ++kk) {
            int koff = kk * 32 + quad * 8;
#pragma unroll
            for (int s = 0; s < 2; ++s) {
                bf16x8 bfr = *(const bf16x8*)(&h_lds[(s * 16 + lrow) * LDH + koff]);
                c[0][s] = __builtin_amdgcn_mfma_f32_16x16x32_bf16(afrag[0][kk], bfr, c[0][s], 0, 0, 0);
                c[1][s] = __builtin_amdgcn_mfma_f32_16x16x32_bf16(afrag[1][kk], bfr, c[1][s], 0, 0, 0);
            }
        }

        if (t0 + NT > len) {   // tail-mask cols t = t0 + s*16 + lrow
#pragma unroll
            for (int s = 0; s < 2; ++s) {
                int t = t0 + s * 16 + lrow;
                if (t >= len) {
#pragma unroll
                    for (int set = 0; set < 2; ++set) {
                        c[set][s][0] = -3.0e38f; c[set][s][1] = -3.0e38f;
                        c[set][s][2] = -3.0e38f; c[set][s][3] = -3.0e38f;
                    }
                }
            }
        }

        float hw0 = hw_lds[lrow], hw1 = hw_lds[16 + lrow];

        // shared-per-lane max over this round's 16 scores
        float cm = fmaxf(fmaxf(fmaxf(c[0][0][0], c[0][0][1]), fmaxf(c[0][0][2], c[0][0][3])),
                         fmaxf(fmaxf(c[0][1][0], c[0][1][1]), fmaxf(c[0][1][2], c[0][1][3])));
        cm = fmaxf(cm,
             fmaxf(fmaxf(fmaxf(c[1][0][0], c[1][0][1]), fmaxf(c[1][0][2], c[1][0][3])),
                   fmaxf(fmaxf(c[1][1][0], c[1][1][1]), fmaxf(c[1][1][2], c[1][1][3]))));
        float mn = fmaxf(m_s, cm);
        float alpha = __expf(m_s - mn);
        m_s = mn;
#pragma unroll
        for (int set = 0; set < 2; ++set)
#pragma unroll
            for (int r = 0; r < 4; ++r) {
                float p0 = __expf(c[set][0][r] - mn);
                float p1 = __expf(c[set][1][r] - mn);
                l_s[set][r] = l_s[set][r] * alpha + (p0 + p1);
                a_s[set][r] = a_s[set][r] * alpha + (p0 * hw0 + p1 * hw1);
            }
    }

    // epilogue: butterfly-merge 16 per-lane states (heterogeneous m is fine)
#pragma unroll
    for (int set = 0; set < 2; ++set)
#pragma unroll
        for (int r = 0; r < 4; ++r) {
            float m = m_s, l = l_s[set][r], a = a_s[set][r];
#pragma unroll
            for (int off = 1; off < 16; off <<= 1) {
                float mo = __shfl_xor(m, off, 64);
                float lo = __shfl_xor(l, off, 64);
                float ao = __shfl_xor(a, off, 64);
                float mx = fmaxf(m, mo);
                float f1 = __expf(m - mx), f2 = __expf(mo - mx);
                l = l * f1 + lo * f2;
                a = a * f1 + ao * f2;
                m = mx;
            }
            if (lrow == 0) {
                int v = vbase + wave * 32 + set * 16 + quad * 4 + r;
                out[(size_t)b * NV + v] = a / l + b0;
            }
        }
}

// ---------------------------------------------------------------------------
extern "C" void kernel_launch(void* const* d_in, const int* in_sizes, int n_in,
                              void* d_out, int out_size, void* d_ws, size_t ws_size,
                              hipStream_t stream) {
    const float* H    = (const float*)d_in[0];   // (B,T,D)
    const float* cu   = (const float*)d_in[1];   // (B,D)
    const float* Ca   = (const float*)d_in[2];   // (B,NA,D)
    const float* Cv   = (const float*)d_in[3];   // (NV,1,D)
    const float* W    = (const float*)d_in[4];   // (1,D)
    const float* bs   = (const float*)d_in[5];   // (1,)
    const int*   lens = (const int*)d_in[6];     // (B,)
    float* out = (float*)d_out;                  // f32: y_utts (B,NV) ++ y_acts (B,NV)

    float*  hw   = (float*)d_ws;                        // B*T f32 (256 KB)
    float*  q_ws = hw + (size_t)B_ * T_;                // B*D f32 (200 KB)
    float*  s2   = q_ws + (size_t)B_ * D_;              // B*NA f32 (64 KB)
    bf16_t* Hbf  = (bf16_t*)(s2 + (size_t)B_ * NA);     // B*T*424 bf16 (55.6 MB)

    size_t need = ((size_t)B_ * T_ + (size_t)B_ * D_ + (size_t)B_ * NA) * sizeof(float)
                + (size_t)B_ * T_ * LDH * sizeof(bf16_t)
                + 4096;                                 // DMA tail-chunk overfetch slack
    bool pre = (ws_size >= need);

    int prep_blocks = B_ * T_ / 4 + B_ * NA / 4;
    if (pre) {
        prep_kernel<<<dim3(prep_blocks), dim3(256), 0, stream>>>(H, W, Ca, cu, hw, Hbf, s2);
    } else {
        prep_nb_kernel<<<dim3(prep_blocks), dim3(256), 0, stream>>>(H, W, Ca, cu, hw, s2);
    }
    qacts_kernel<<<dim3(B_), dim3(256), 0, stream>>>(s2, Ca, q_ws);
    int fused_blocks = MAIN_BLOCKS + B_ * NV / 16;
    if (pre) {
        main_kernel<1><<<dim3(fused_blocks), dim3(256), 0, stream>>>(H, Hbf, Cv, hw, bs, lens, q_ws, out);
    } else {
        main_kernel<0><<<dim3(fused_blocks), dim3(256), 0, stream>>>(H, Hbf, Cv, hw, bs, lens, q_ws, out);
    }
}